// Round 4
// baseline (73.201 us; speedup 1.0000x reference)
//
#include <hip/hip_runtime.h>
#include <math.h>

// CapsuleLayer routing collapses (verified R1-R3, absmax 0.0):
//   out[b,j,d] = squash_d( (1/N) * sum_{n,i} x[b,n,i] * W[n,i,d] )  for all j.
// R3 post-mortem: timed region is dominated by the harness's 268 MB d_ws
// poison fill (40.5 us @ 83% HBM peak, its own roofline). Our controllable
// remainder is dispatch count + kernel time. R4: fuse to ONE dispatch.
//   64 blocks (1/batch) x 1024 threads: W read exactly once per batch,
//   in-register shfl_xor reduction, one LDS stage, coalesced f4 broadcast
//   write of the batch's 72 KB output slice. d_ws unused.

#define BATCH 64
#define NCAPS 1152
// per batch: 9216 (n,i) pairs; W = 36864 floats = 9216 float4

__global__ __launch_bounds__(1024) void caps_fused(
    const float* __restrict__ x,   // [B, N, 8]
    const float* __restrict__ W,   // [1, N, 8, 16]
    float* __restrict__ out)       // [B, N, 16]
{
    const int b      = blockIdx.x;
    const int t      = threadIdx.x;
    const int dg     = t & 3;      // float4 group within the 16-dim output
    const int stripe = t >> 2;     // 0..255 pair-stripe

    const float*  xb = x + (size_t)b * 9216;
    const float4* W4 = (const float4*)W + dg;

    // pairs p = k*256 + stripe; W float4 index = 4p + dg.
    // Lane layout (dg fast, stripe next): a wave reads 1 KB contiguous W per k,
    // and 16 consecutive x scalars broadcast across their 4 dg-lanes.
    float4 acc[4];
#pragma unroll
    for (int a = 0; a < 4; ++a) acc[a] = make_float4(0.f, 0.f, 0.f, 0.f);
#pragma unroll 4
    for (int k = 0; k < 36; ++k) {
        const int p = k * 256 + stripe;
        const float  xs = xb[p];
        const float4 w  = W4[4 * p];
        float4& a = acc[k & 3];
        a.x += xs * w.x; a.y += xs * w.y;
        a.z += xs * w.z; a.w += xs * w.w;
    }
    float4 r;
    r.x = (acc[0].x + acc[1].x) + (acc[2].x + acc[3].x);
    r.y = (acc[0].y + acc[1].y) + (acc[2].y + acc[3].y);
    r.z = (acc[0].z + acc[1].z) + (acc[2].z + acc[3].z);
    r.w = (acc[0].w + acc[1].w) + (acc[2].w + acc[3].w);

    // in-wave reduce over the 16 stripes resident in lane bits 2..5
#pragma unroll
    for (int m = 4; m <= 32; m <<= 1) {
        r.x += __shfl_xor(r.x, m, 64);
        r.y += __shfl_xor(r.y, m, 64);
        r.z += __shfl_xor(r.z, m, 64);
        r.w += __shfl_xor(r.w, m, 64);
    }

    __shared__ float4 wred[64];        // [wave][dg]
    __shared__ float  ubar[16];
    const int wave = t >> 6;
    const int lane = t & 63;
    if (lane < 4) wred[wave * 4 + dg] = r;   // lane == dg here
    __syncthreads();

    if (t < 64) {                      // wave 0: sum the 16 per-wave partials
        const int w = t >> 2, d = t & 3;
        float4 v = wred[w * 4 + d];
#pragma unroll
        for (int m = 4; m <= 32; m <<= 1) {
            v.x += __shfl_xor(v.x, m, 64);
            v.y += __shfl_xor(v.y, m, 64);
            v.z += __shfl_xor(v.z, m, 64);
            v.w += __shfl_xor(v.w, m, 64);
        }
        if (t < 4) {                   // t == d
            const float inv = 1.0f / (float)NCAPS;
            ubar[t * 4 + 0] = v.x * inv; ubar[t * 4 + 1] = v.y * inv;
            ubar[t * 4 + 2] = v.z * inv; ubar[t * 4 + 3] = v.w * inv;
        }
    }
    __syncthreads();

    // squash (redundant per thread; LDS broadcast reads are free)
    float sq = 0.f;
#pragma unroll
    for (int d = 0; d < 16; ++d) sq += ubar[d] * ubar[d];
    const float scale = sq / (1.0f + sq) / sqrtf(sq + 1e-8f);

    float4 v4[4];
#pragma unroll
    for (int g = 0; g < 4; ++g)
        v4[g] = make_float4(scale * ubar[4 * g + 0], scale * ubar[4 * g + 1],
                            scale * ubar[4 * g + 2], scale * ubar[4 * g + 3]);

    // broadcast write: batch slice = 1152*16 floats = 4608 float4
    float4* out4 = (float4*)out + (size_t)b * 4608;
    for (int idx = t; idx < 4608; idx += 1024)
        out4[idx] = v4[idx & 3];
}

extern "C" void kernel_launch(void* const* d_in, const int* in_sizes, int n_in,
                              void* d_out, int out_size, void* d_ws, size_t ws_size,
                              hipStream_t stream) {
    const float* x = (const float*)d_in[0];
    const float* W = (const float*)d_in[1];
    float* out     = (float*)d_out;
    caps_fused<<<BATCH, 1024, 0, stream>>>(x, W, out);
}

// Round 5
// 63.408 us; speedup vs baseline: 1.1544x; 1.1544x over previous
//
#include <hip/hip_runtime.h>
#include <math.h>

// CapsuleLayer routing collapses (verified R1-R4, absmax 0.0):
//   out[b,j,d] = squash_d( (1/N) * sum_{n,i} x[b,n,i] * W[n,i,d] )  for all j.
//
// R4 post-mortem: fused-64-block version regressed (73us). Suspects:
//   (a) 64 blocks = 1/4 of machine for the 4.7MB write phase;
//   (b) v4[idx&3] register-array dynamic indexing -> cndmask/scratch in the
//       store loop (R1 had the same pattern and was also mysteriously slow;
//       R2/R3's direct per-thread float4 K2s were fast).
// R5: keep single dispatch, fix both: 256 blocks (4 j-chunks/batch, 1/CU,
// full-machine write), and each thread computes exactly ONE float4 directly
// from LDS ubar (t&3 group; both store indices are ==t mod 4). 4x redundant
// W reads = 147MB L2-resident (~4us) buys zero cross-block communication.

#define BATCH 64
#define NCAPS 1152
// per batch: 9216 (n,i) pairs; W = 9216 float4; out slice = 4608 float4

__global__ __launch_bounds__(1024) void caps_fused(
    const float* __restrict__ x,   // [B, N, 8]
    const float* __restrict__ W,   // [1, N, 8, 16]
    float* __restrict__ out)       // [B, N, 16]
{
    const int b      = blockIdx.x >> 2;
    const int c      = blockIdx.x & 3;     // j-chunk 0..3
    const int t      = threadIdx.x;
    const int dg     = t & 3;              // float4 group of the 16-dim output
    const int stripe = t >> 2;             // 0..255 pair-stripe

    const float*  xb = x + (size_t)b * 9216;
    const float4* W4 = (const float4*)W + dg;

    // Full-batch reduction (redundant across the 4 c-blocks of this batch).
    // p = k*256 + stripe; W float4 idx = 4p + dg: each wave reads 1 KB of
    // contiguous W per k; x scalars broadcast across the 4 dg-lanes.
    float4 a0 = make_float4(0.f,0.f,0.f,0.f), a1 = a0, a2 = a0, a3 = a0;
#pragma unroll
    for (int k = 0; k < 36; k += 4) {
        const int p0 = k * 256 + stripe;
        float  xs;
        float4 w;
        xs = xb[p0];        w = W4[4*p0];
        a0.x += xs*w.x; a0.y += xs*w.y; a0.z += xs*w.z; a0.w += xs*w.w;
        xs = xb[p0+256];    w = W4[4*(p0+256)];
        a1.x += xs*w.x; a1.y += xs*w.y; a1.z += xs*w.z; a1.w += xs*w.w;
        xs = xb[p0+512];    w = W4[4*(p0+512)];
        a2.x += xs*w.x; a2.y += xs*w.y; a2.z += xs*w.z; a2.w += xs*w.w;
        xs = xb[p0+768];    w = W4[4*(p0+768)];
        a3.x += xs*w.x; a3.y += xs*w.y; a3.z += xs*w.z; a3.w += xs*w.w;
    }
    float4 r;
    r.x = (a0.x + a1.x) + (a2.x + a3.x);
    r.y = (a0.y + a1.y) + (a2.y + a3.y);
    r.z = (a0.z + a1.z) + (a2.z + a3.z);
    r.w = (a0.w + a1.w) + (a2.w + a3.w);

    // reduce over the 16 stripes resident in lane bits 2..5 (in-register)
#pragma unroll
    for (int m = 4; m <= 32; m <<= 1) {
        r.x += __shfl_xor(r.x, m, 64);
        r.y += __shfl_xor(r.y, m, 64);
        r.z += __shfl_xor(r.z, m, 64);
        r.w += __shfl_xor(r.w, m, 64);
    }

    __shared__ float4 wred[64];            // [wave][dg], flat index = wave*4+dg
    __shared__ float  ubar[16];
    const int wave = t >> 6;
    const int lane = t & 63;
    if (lane < 4) wred[wave * 4 + dg] = r; // lane == dg here
    __syncthreads();

    if (t < 64) {                          // wave 0: flat load, shfl over waves
        float4 v = wred[t];                // t = w*4 + d
#pragma unroll
        for (int m = 4; m <= 32; m <<= 1) { // sums over w (bits 2..5)
            v.x += __shfl_xor(v.x, m, 64);
            v.y += __shfl_xor(v.y, m, 64);
            v.z += __shfl_xor(v.z, m, 64);
            v.w += __shfl_xor(v.w, m, 64);
        }
        if (t < 4) {                       // t == d
            const float inv = 1.0f / (float)NCAPS;
            ubar[t * 4 + 0] = v.x * inv; ubar[t * 4 + 1] = v.y * inv;
            ubar[t * 4 + 2] = v.z * inv; ubar[t * 4 + 3] = v.w * inv;
        }
    }
    __syncthreads();

    // squash (redundant per thread; LDS broadcast reads)
    float sq = 0.f;
#pragma unroll
    for (int d = 0; d < 16; ++d) sq += ubar[d] * ubar[d];
    const float scale = sq / (1.0f + sq) / sqrtf(sq + 1e-8f);

    // ONE float4 per thread, no register-array indexing: both of this
    // thread's store indices (t and t+1024) are == t (mod 4).
    const float4 v = make_float4(scale * ubar[dg * 4 + 0],
                                 scale * ubar[dg * 4 + 1],
                                 scale * ubar[dg * 4 + 2],
                                 scale * ubar[dg * 4 + 3]);

    // chunk c: 288 j's = 1152 float4, perfectly coalesced
    float4* out4 = (float4*)out + (size_t)b * 4608 + (size_t)c * 1152;
    out4[t] = v;
    if (t < 128) out4[1024 + t] = v;
}

extern "C" void kernel_launch(void* const* d_in, const int* in_sizes, int n_in,
                              void* d_out, int out_size, void* d_ws, size_t ws_size,
                              hipStream_t stream) {
    const float* x = (const float*)d_in[0];
    const float* W = (const float*)d_in[1];
    float* out     = (float*)d_out;
    caps_fused<<<BATCH * 4, 1024, 0, stream>>>(x, W, out);
}

// Round 6
// 62.334 us; speedup vs baseline: 1.1743x; 1.0172x over previous
//
#include <hip/hip_runtime.h>
#include <math.h>

// CapsuleLayer routing collapses (verified R1-R5, absmax 0.0):
//   out[b,j,d] = squash_d( (1/N) * sum_{n,i} x[b,n,i] * W[n,i,d] )  for all j.
// == C[64,16] = X[64,9216] . W[9216,16], then squash rows, broadcast over j.
//
// R5 post-mortem: fused single-kernel is structurally worse (each writing
// block needs full ubar -> 147MB redundant W traffic). Two-kernel split-K:
//   K1: 256 K-slices, x & W staged to LDS and read from global EXACTLY once
//       (3MB total); thread owns (b,dg), zero intra-block reduction; 1MB ws.
//   K2: coalesced per-batch ws slab reduce + squash + 1 f4 store/thread.
// Timed-region floor is harness-owned: 268MB d_ws poison fill = 41us @ 81%
// HBM peak (its own roofline) + fills/restores + graph-node overheads.

#define BATCH  64
#define NCAPS  1152
#define KTOT   9216        // NCAPS * IN_DIM (n,i) pairs
#define SLICES 256
#define PAIRS  36          // KTOT / SLICES

// ---- K1: grid = 256 (one K-slice each), block = 256 ----
__global__ __launch_bounds__(256) void caps_gemm(
    const float* __restrict__ x,   // [64][9216]
    const float* __restrict__ W,   // [9216][16]
    float* __restrict__ ws)        // [64][256][16] floats = 1 MB
{
    const int s = blockIdx.x;
    const int t = threadIdx.x;

    __shared__ float4 Wsh[PAIRS * 4];      // [p][dg]  2.3 KB
    __shared__ float  xsh[BATCH * PAIRS];  // [b][p]   9.2 KB

    // stage W-slice: 144 contiguous float4
    if (t < PAIRS * 4) Wsh[t] = ((const float4*)W)[s * (PAIRS * 4) + t];
    // stage x-slice: 2304 floats, 9 per thread; e = b*36 + p
#pragma unroll
    for (int i = 0; i < 9; ++i) {
        const int e = t + 256 * i;
        const int b = e / PAIRS;
        const int p = e - b * PAIRS;
        xsh[e] = x[(size_t)b * KTOT + s * PAIRS + p];
    }
    __syncthreads();

    // thread owns (b, dg): full 36-pair dot for 4 output dims, no reduction
    const int b  = t >> 2;
    const int dg = t & 3;
    const float* xr = xsh + b * PAIRS;
    float4 acc = make_float4(0.f, 0.f, 0.f, 0.f);
#pragma unroll
    for (int p = 0; p < PAIRS; ++p) {
        const float  xs = xr[p];               // 4-lane broadcast, 2-way bank
        const float4 w  = Wsh[p * 4 + dg];     // 4 distinct b128, broadcast
        acc.x += xs * w.x; acc.y += xs * w.y;
        acc.z += xs * w.z; acc.w += xs * w.w;
    }
    // ws layout [b][s][dg] so K2 reads a contiguous per-batch slab
    ((float4*)ws)[(size_t)b * (SLICES * 4) + s * 4 + dg] = acc;
}

// ---- K2: grid = 64*18 = 1152, block = 256 ----
__global__ __launch_bounds__(256) void caps_write(
    const float* __restrict__ ws, float* __restrict__ out)
{
    const int blk = blockIdx.x;
    const int b   = blk / 18;
    const int t   = threadIdx.x;
    const int dg  = t & 3;

    // batch slab = 1024 float4 contiguous; 4 coalesced f4 reads per thread
    const float4* wb = (const float4*)ws + (size_t)b * (SLICES * 4);
    float4 v = make_float4(0.f, 0.f, 0.f, 0.f);
#pragma unroll
    for (int g = 0; g < 4; ++g) {
        const float4 a = wb[g * 256 + t];
        v.x += a.x; v.y += a.y; v.z += a.z; v.w += a.w;
    }
    // sum over the 16 slice-groups resident in lane bits 2..5
#pragma unroll
    for (int m = 4; m <= 32; m <<= 1) {
        v.x += __shfl_xor(v.x, m, 64);
        v.y += __shfl_xor(v.y, m, 64);
        v.z += __shfl_xor(v.z, m, 64);
        v.w += __shfl_xor(v.w, m, 64);
    }

    __shared__ float4 wred[16];    // [wave][dg]
    __shared__ float  ubar[16];
    const int wave = t >> 6;
    const int lane = t & 63;
    if (lane < 4) wred[wave * 4 + dg] = v;   // lane == dg here
    __syncthreads();

    if (t < 4) {                   // t == dg: combine the 4 waves
        const float4 a = wred[t],     b4 = wred[4 + t];
        const float4 c = wred[8 + t], d4 = wred[12 + t];
        float4 r;
        r.x = (a.x + b4.x) + (c.x + d4.x);
        r.y = (a.y + b4.y) + (c.y + d4.y);
        r.z = (a.z + b4.z) + (c.z + d4.z);
        r.w = (a.w + b4.w) + (c.w + d4.w);
        const float inv = 1.0f / (float)NCAPS;
        ubar[t * 4 + 0] = r.x * inv; ubar[t * 4 + 1] = r.y * inv;
        ubar[t * 4 + 2] = r.z * inv; ubar[t * 4 + 3] = r.w * inv;
    }
    __syncthreads();

    float sq = 0.f;
#pragma unroll
    for (int d = 0; d < 16; ++d) sq += ubar[d] * ubar[d];
    const float scale = sq / (1.0f + sq) / sqrtf(sq + 1e-8f);

    const float4 o = make_float4(scale * ubar[dg * 4 + 0],
                                 scale * ubar[dg * 4 + 1],
                                 scale * ubar[dg * 4 + 2],
                                 scale * ubar[dg * 4 + 3]);
    ((float4*)out)[(size_t)blk * 256 + t] = o;   // one coalesced store/thread
}

extern "C" void kernel_launch(void* const* d_in, const int* in_sizes, int n_in,
                              void* d_out, int out_size, void* d_ws, size_t ws_size,
                              hipStream_t stream) {
    const float* x = (const float*)d_in[0];
    const float* W = (const float*)d_in[1];
    float* out     = (float*)d_out;
    float* ws      = (float*)d_ws;   // 1 MB used

    caps_gemm <<<SLICES,     256, 0, stream>>>(x, W, ws);
    caps_write<<<BATCH * 18, 256, 0, stream>>>(ws, out);
}